// Round 3
// baseline (1073.590 us; speedup 1.0000x reference)
//
#include <hip/hip_runtime.h>
#include <stdint.h>

// All inputs/outputs are FP32 (reference dtype). Compute in bf16 MFMA with
// hi/lo split precision on the attn-critical path (qkv -> Q,K -> S -> P).
#define D_MODEL 1024
#define NHEAD   16
#define BATCH   2
#define SEQ     2048
#define MROWS   (BATCH*SEQ)                  // 4096
#define OUT0_ELEMS (MROWS*D_MODEL)           // 4194304
#define W_ELEMS    (D_MODEL*D_MODEL)

// workspace offsets (ushort-element index unless noted); total 72,351,744 B
#define U_QKV_HI  0            // bf16 hi(qkv)           (later aliased by Ob)
#define U_QKV_LO  4194304      // bf16 lo(qkv)           (later aliased by Gf)
#define U_WQ_HI   8388608
#define U_WQ_LO   9437184
#define U_WK_HI   10485760
#define U_WK_LO   11534336
#define U_WV      12582912
#define U_WFC     13631488
#define F_Q       7340032      // float index (byte 29360128)
#define F_K       11534336     // float index (byte 46137344)
#define U_VT      31457280     // byte 62914560
#define B_MB      71303168     // byte offset of mask bits
#define F_G       2097152      // float index (byte 8388608), aliases lo+wq/wk

typedef __bf16  bf16x8 __attribute__((ext_vector_type(8)));
typedef float   f32x4  __attribute__((ext_vector_type(4)));

__device__ __forceinline__ float bf2f(unsigned short u) {
    union { unsigned int ui; float f; } v; v.ui = ((unsigned int)u) << 16; return v.f;
}
__device__ __forceinline__ unsigned short f2bf(float f) {
    union { float f; unsigned int u; } v; v.f = f;
    unsigned int u = v.u;
    return (unsigned short)((u + 0x7FFFu + ((u >> 16) & 1u)) >> 16);  // RNE
}
__device__ __forceinline__ void split2(float x, unsigned short& hi, unsigned short& lo) {
    hi = f2bf(x);
    lo = f2bf(x - bf2f(hi));   // x-hi exact in fp32; combined rel err ~2^-18
}

// ---------------------------------------------------------------------------
// 1) qkv fp32 -> hi/lo bf16 arrays
__global__ void k_split(const float* in, unsigned short* hiA, unsigned short* loA)
{
    int i = (blockIdx.x * 256 + threadIdx.x) * 4;
    float4 x = *(const float4*)&in[i];
    ushort4 h, l;
    split2(x.x, h.x, l.x); split2(x.y, h.y, l.y);
    split2(x.z, h.z, l.z); split2(x.w, h.w, l.w);
    *(ushort4*)&hiA[i] = h;
    *(ushort4*)&loA[i] = l;
}

// ---------------------------------------------------------------------------
// 2) weight fp32 [k][n] -> transposed [n][k]; z=0,1 (wq,wk): hi+lo; z=2,3: plain
__global__ void k_wtrans(const float* w0, const float* w1, const float* w2,
                         const float* w3, unsigned short* R)
{
    __shared__ __align__(16) float T[64][68];
    int z = blockIdx.z;
    const float* in = (z == 0) ? w0 : (z == 1) ? w1 : (z == 2) ? w2 : w3;
    const int hiOff[4] = {U_WQ_HI, U_WK_HI, U_WV, U_WFC};
    const int loOff[2] = {U_WQ_LO, U_WK_LO};
    unsigned short* outH = R + hiOff[z];
    unsigned short* outL = (z < 2) ? (R + loOff[z]) : nullptr;
    int bn = blockIdx.x, bk = blockIdx.y, tid = threadIdx.x;
    int r0 = tid >> 4, c = (tid & 15) * 4;
    for (int i = 0; i < 4; i++) {
        int r = r0 + i * 16;
        *(float4*)&T[r][c] = *(const float4*)&in[(bk*64 + r)*1024 + bn*64 + c];
    }
    __syncthreads();
    for (int i = 0; i < 4; i++) {
        int r = r0 + i * 16;          // n-local
        ushort4 h, l;
        split2(T[c+0][r], h.x, l.x); split2(T[c+1][r], h.y, l.y);
        split2(T[c+2][r], h.z, l.z); split2(T[c+3][r], h.w, l.w);
        *(ushort4*)&outH[(bn*64 + r)*1024 + bk*64 + c] = h;
        if (z < 2) *(ushort4*)&outL[(bn*64 + r)*1024 + bk*64 + c] = l;
    }
}

// ---------------------------------------------------------------------------
// 3) Bit-pack mask: word w covers flat ints w*64..w*64+63
__global__ void k_maskpack(const int* mask, unsigned long long* mb)
{
    int w = blockIdx.x * 4 + (threadIdx.x >> 6);
    int lane = threadIdx.x & 63;
    int v = mask[(size_t)w * 64 + lane];
    unsigned long long bal = __ballot(v != 0);
    if (lane == 0) mb[w] = bal;
}

// ---------------------------------------------------------------------------
// 4) Split-precision GEMM for Q (z=0, scale 1/8) and K (z=1), fp32 out.
//    acc += Ah*Bh + Ah*Bl + Al*Bh  (lo*lo dropped, ~2^-18)
__global__ __launch_bounds__(256)
void k_gemm_qk(const unsigned short* R, float* ws_f)
{
    __shared__ __align__(16) unsigned short Ah[8192], Al[8192];
    __shared__ __align__(16) unsigned short Bh[8192], Bl[8192];
    int tid = threadIdx.x, wv = tid >> 6, lane = tid & 63;
    int quad = lane >> 4, l15 = lane & 15;
    int m0 = blockIdx.y * 128, n0 = blockIdx.x * 128;
    int z = blockIdx.z;
    const unsigned short* Ahg = R + U_QKV_HI;
    const unsigned short* Alg = R + U_QKV_LO;
    const unsigned short* Bhg = R + (z == 0 ? U_WQ_HI : U_WK_HI);
    const unsigned short* Blg = R + (z == 0 ? U_WQ_LO : U_WK_LO);
    float* out = ws_f + (z == 0 ? F_Q : F_K);
    float scale = (z == 0) ? 0.125f : 1.0f;

    f32x4 zero4 = {0.f, 0.f, 0.f, 0.f};
    f32x4 acc[4][4];
    for (int a = 0; a < 4; a++) for (int b = 0; b < 4; b++) acc[a][b] = zero4;
    int wr = (wv >> 1) * 64, wc = (wv & 1) * 64;

    for (int k0 = 0; k0 < 1024; k0 += 64) {
        __syncthreads();
        for (int i = 0; i < 4; i++) {
            int e = (tid + 256*i) * 8, row = e >> 6, col = e & 63;
            *(uint4*)&Ah[e] = *(const uint4*)&Ahg[(m0+row)*1024 + k0 + col];
            *(uint4*)&Al[e] = *(const uint4*)&Alg[(m0+row)*1024 + k0 + col];
            *(uint4*)&Bh[e] = *(const uint4*)&Bhg[(n0+row)*1024 + k0 + col];
            *(uint4*)&Bl[e] = *(const uint4*)&Blg[(n0+row)*1024 + k0 + col];
        }
        __syncthreads();
        #pragma unroll
        for (int kc = 0; kc < 2; kc++) {
            bf16x8 ah[4], al[4], bh[4], bl[4];
            #pragma unroll
            for (int t = 0; t < 4; t++) {
                int ao = (wr + t*16 + l15)*64 + kc*32 + quad*8;
                int bo = (wc + t*16 + l15)*64 + kc*32 + quad*8;
                ah[t] = *(const bf16x8*)&Ah[ao];
                al[t] = *(const bf16x8*)&Al[ao];
                bh[t] = *(const bf16x8*)&Bh[bo];
                bl[t] = *(const bf16x8*)&Bl[bo];
            }
            #pragma unroll
            for (int tm = 0; tm < 4; tm++)
                #pragma unroll
                for (int tn = 0; tn < 4; tn++) {
                    acc[tm][tn] = __builtin_amdgcn_mfma_f32_16x16x32_bf16(ah[tm], bh[tn], acc[tm][tn], 0,0,0);
                    acc[tm][tn] = __builtin_amdgcn_mfma_f32_16x16x32_bf16(ah[tm], bl[tn], acc[tm][tn], 0,0,0);
                    acc[tm][tn] = __builtin_amdgcn_mfma_f32_16x16x32_bf16(al[tm], bh[tn], acc[tm][tn], 0,0,0);
                }
        }
    }
    for (int tm = 0; tm < 4; tm++) for (int tn = 0; tn < 4; tn++)
        for (int r = 0; r < 4; r++) {
            int row = m0 + wr + tm*16 + quad*4 + r;
            int col = n0 + wc + tn*16 + l15;
            out[(size_t)row*1024 + col] = acc[tm][tn][r] * scale;
        }
}

// ---------------------------------------------------------------------------
// 5) Plain bf16 GEMM. mode 0: V-proj -> Vt bf16 [b,h,d,s]. mode 1: FC ->
//    Gf fp32 = A@B^T + residual(fp32 original qkv).
__global__ __launch_bounds__(256)
void k_gemm_bf(const unsigned short* A, const unsigned short* Bt,
               unsigned short* Vt, float* Gf, const float* resf, int mode)
{
    __shared__ __align__(16) unsigned short As[8192];
    __shared__ __align__(16) unsigned short Bs[8192];
    int tid = threadIdx.x, wv = tid >> 6, lane = tid & 63;
    int quad = lane >> 4, l15 = lane & 15;
    int m0 = blockIdx.y * 128, n0 = blockIdx.x * 128;
    f32x4 zero4 = {0.f, 0.f, 0.f, 0.f};
    f32x4 acc[4][4];
    for (int a = 0; a < 4; a++) for (int b = 0; b < 4; b++) acc[a][b] = zero4;
    int wr = (wv >> 1) * 64, wc = (wv & 1) * 64;

    for (int k0 = 0; k0 < 1024; k0 += 64) {
        __syncthreads();
        for (int i = 0; i < 4; i++) {
            int e = (tid + 256*i) * 8, row = e >> 6, col = e & 63;
            *(uint4*)&As[e] = *(const uint4*)&A [(m0+row)*1024 + k0 + col];
            *(uint4*)&Bs[e] = *(const uint4*)&Bt[(n0+row)*1024 + k0 + col];
        }
        __syncthreads();
        #pragma unroll
        for (int kc = 0; kc < 2; kc++) {
            bf16x8 af[4], bfr[4];
            #pragma unroll
            for (int t = 0; t < 4; t++) {
                af[t]  = *(const bf16x8*)&As[(wr + t*16 + l15)*64 + kc*32 + quad*8];
                bfr[t] = *(const bf16x8*)&Bs[(wc + t*16 + l15)*64 + kc*32 + quad*8];
            }
            #pragma unroll
            for (int tm = 0; tm < 4; tm++)
                #pragma unroll
                for (int tn = 0; tn < 4; tn++)
                    acc[tm][tn] = __builtin_amdgcn_mfma_f32_16x16x32_bf16(
                        af[tm], bfr[tn], acc[tm][tn], 0, 0, 0);
        }
    }
    for (int tm = 0; tm < 4; tm++) for (int tn = 0; tn < 4; tn++)
        for (int r = 0; r < 4; r++) {
            int row = m0 + wr + tm*16 + quad*4 + r;
            int col = n0 + wc + tn*16 + l15;
            float v = acc[tm][tn][r];
            if (mode == 1) {
                Gf[(size_t)row*1024 + col] = v + resf[(size_t)row*1024 + col];
            } else {
                int b = row >> 11, s = row & 2047, h = col >> 6, d = col & 63;
                Vt[(size_t)(((b*16 + h)*64 + d))*2048 + s] = f2bf(v);
            }
        }
}

// ---------------------------------------------------------------------------
// 6) Attention. Q,K fp32 -> hi/lo split QK^T (3 MFMAs), two-sweep no-max
//    softmax (|s| small -> fp32 exp safe). P written fp32 to d_out; PV plain.
__global__ __launch_bounds__(256)
void k_attn(const float* Q, const float* K, const unsigned short* Vt,
            const unsigned long long* mb, float* Pout, unsigned short* Obuf)
{
    __shared__ __align__(16) unsigned short Qh[128*64], Ql[128*64];
    __shared__ __align__(16) unsigned short Kh[32*64],  Kl[32*64];
    __shared__ __align__(16) unsigned short Vs[64*32];
    __shared__ __align__(16) unsigned short Ps[128*32];
    int tid = threadIdx.x, wv = tid >> 6, lane = tid & 63;
    int quad = lane >> 4, l15 = lane & 15;
    int h = blockIdx.x, qt = blockIdx.y, b = blockIdx.z;

    const float* Qb = Q + (size_t)(b*2048 + qt*128)*1024 + h*64;
    const float* Kb = K + (size_t)b*2048*1024 + h*64;
    const unsigned short* Vtb = Vt + (size_t)((b*16 + h)*64)*2048;
    const unsigned long long* Mb = mb + (size_t)(b*2048 + qt*128)*32;
    float* Pg = Pout + (size_t)((b*16 + h)*2048 + qt*128)*2048;

    for (int i = 0; i < 8; i++) {            // stage Q 128x64 fp32 -> hi/lo
        int e = (tid + 256*i)*4, row = e >> 6, col = e & 63;
        float4 x = *(const float4*)&Qb[(size_t)row*1024 + col];
        ushort4 hv, lv;
        split2(x.x, hv.x, lv.x); split2(x.y, hv.y, lv.y);
        split2(x.z, hv.z, lv.z); split2(x.w, hv.w, lv.w);
        *(ushort4*)&Qh[row*64 + col] = hv;
        *(ushort4*)&Ql[row*64 + col] = lv;
    }

    float lsum[8];
    for (int r = 0; r < 8; r++) lsum[r] = 0.f;
    f32x4 zero4 = {0.f, 0.f, 0.f, 0.f};

    // ---- sweep 1: denominators
    for (int kt = 0; kt < 64; kt++) {
        __syncthreads();
        for (int i = 0; i < 2; i++) {
            int e = (tid + 256*i)*4, row = e >> 6, col = e & 63;   // row 0..31
            float4 x = *(const float4*)&Kb[(size_t)(kt*32 + row)*1024 + col];
            ushort4 hv, lv;
            split2(x.x, hv.x, lv.x); split2(x.y, hv.y, lv.y);
            split2(x.z, hv.z, lv.z); split2(x.w, hv.w, lv.w);
            *(ushort4*)&Kh[row*64 + col] = hv;
            *(ushort4*)&Kl[row*64 + col] = lv;
        }
        __syncthreads();
        f32x4 sacc[2][2];
        for (int a = 0; a < 2; a++) for (int c = 0; c < 2; c++) sacc[a][c] = zero4;
        #pragma unroll
        for (int kc = 0; kc < 2; kc++) {
            bf16x8 qh[2], ql[2], kh[2], kl[2];
            #pragma unroll
            for (int t = 0; t < 2; t++) {
                int qo = (wv*32 + t*16 + l15)*64 + kc*32 + quad*8;
                int ko = (t*16 + l15)*64 + kc*32 + quad*8;
                qh[t] = *(const bf16x8*)&Qh[qo]; ql[t] = *(const bf16x8*)&Ql[qo];
                kh[t] = *(const bf16x8*)&Kh[ko]; kl[t] = *(const bf16x8*)&Kl[ko];
            }
            #pragma unroll
            for (int tm = 0; tm < 2; tm++)
                #pragma unroll
                for (int tn = 0; tn < 2; tn++) {
                    sacc[tm][tn] = __builtin_amdgcn_mfma_f32_16x16x32_bf16(qh[tm], kh[tn], sacc[tm][tn], 0,0,0);
                    sacc[tm][tn] = __builtin_amdgcn_mfma_f32_16x16x32_bf16(qh[tm], kl[tn], sacc[tm][tn], 0,0,0);
                    sacc[tm][tn] = __builtin_amdgcn_mfma_f32_16x16x32_bf16(ql[tm], kh[tn], sacc[tm][tn], 0,0,0);
                }
        }
        #pragma unroll
        for (int tm = 0; tm < 2; tm++)
            #pragma unroll
            for (int r = 0; r < 4; r++) {
                int row = wv*32 + tm*16 + quad*4 + r;
                unsigned long long w = Mb[row*32 + (kt >> 1)];
                int base = (kt & 1) * 32;
                float acc = 0.f;
                #pragma unroll
                for (int tn = 0; tn < 2; tn++)
                    if ((w >> (base + tn*16 + l15)) & 1ull) acc += __expf(sacc[tm][tn][r]);
                lsum[tm*4 + r] += acc;
            }
    }
    float invl[8];
    for (int r = 0; r < 8; r++) {
        float v = lsum[r];
        v += __shfl_xor(v, 1); v += __shfl_xor(v, 2);
        v += __shfl_xor(v, 4); v += __shfl_xor(v, 8);
        invl[r] = 1.0f / fmaxf(v, 1e-30f);
    }

    f32x4 oacc[2][4];
    for (int a = 0; a < 2; a++) for (int c = 0; c < 4; c++) oacc[a][c] = zero4;

    // ---- sweep 2: recompute S, write P (fp32 global + bf16 LDS), PV
    for (int kt = 0; kt < 64; kt++) {
        __syncthreads();
        for (int i = 0; i < 2; i++) {
            int e = (tid + 256*i)*4, row = e >> 6, col = e & 63;
            float4 x = *(const float4*)&Kb[(size_t)(kt*32 + row)*1024 + col];
            ushort4 hv, lv;
            split2(x.x, hv.x, lv.x); split2(x.y, hv.y, lv.y);
            split2(x.z, hv.z, lv.z); split2(x.w, hv.w, lv.w);
            *(ushort4*)&Kh[row*64 + col] = hv;
            *(ushort4*)&Kl[row*64 + col] = lv;
        }
        {   // stage V 64(d) x 32(s): one uint4 per thread
            int d = tid >> 2, sl = (tid & 3) * 8;
            *(uint4*)&Vs[d*32 + sl] = *(const uint4*)&Vtb[(size_t)d*2048 + kt*32 + sl];
        }
        __syncthreads();
        f32x4 sacc[2][2];
        for (int a = 0; a < 2; a++) for (int c = 0; c < 2; c++) sacc[a][c] = zero4;
        #pragma unroll
        for (int kc = 0; kc < 2; kc++) {
            bf16x8 qh[2], ql[2], kh[2], kl[2];
            #pragma unroll
            for (int t = 0; t < 2; t++) {
                int qo = (wv*32 + t*16 + l15)*64 + kc*32 + quad*8;
                int ko = (t*16 + l15)*64 + kc*32 + quad*8;
                qh[t] = *(const bf16x8*)&Qh[qo]; ql[t] = *(const bf16x8*)&Ql[qo];
                kh[t] = *(const bf16x8*)&Kh[ko]; kl[t] = *(const bf16x8*)&Kl[ko];
            }
            #pragma unroll
            for (int tm = 0; tm < 2; tm++)
                #pragma unroll
                for (int tn = 0; tn < 2; tn++) {
                    sacc[tm][tn] = __builtin_amdgcn_mfma_f32_16x16x32_bf16(qh[tm], kh[tn], sacc[tm][tn], 0,0,0);
                    sacc[tm][tn] = __builtin_amdgcn_mfma_f32_16x16x32_bf16(qh[tm], kl[tn], sacc[tm][tn], 0,0,0);
                    sacc[tm][tn] = __builtin_amdgcn_mfma_f32_16x16x32_bf16(ql[tm], kh[tn], sacc[tm][tn], 0,0,0);
                }
        }
        #pragma unroll
        for (int tm = 0; tm < 2; tm++)
            #pragma unroll
            for (int r = 0; r < 4; r++) {
                int row = wv*32 + tm*16 + quad*4 + r;
                unsigned long long w = Mb[row*32 + (kt >> 1)];
                int base = (kt & 1) * 32;
                float il = invl[tm*4 + r];
                #pragma unroll
                for (int tn = 0; tn < 2; tn++) {
                    float p = ((w >> (base + tn*16 + l15)) & 1ull)
                              ? __expf(sacc[tm][tn][r]) * il : 0.0f;
                    Ps[row*32 + tn*16 + l15] = f2bf(p);
                    Pg[(size_t)row*2048 + kt*32 + tn*16 + l15] = p;
                }
            }
        __syncthreads();
        {   // PV: contraction = 32 keys (single K=32 MFMA step)
            bf16x8 ap[2], bv[4];
            #pragma unroll
            for (int t = 0; t < 2; t++)
                ap[t] = *(const bf16x8*)&Ps[(wv*32 + t*16 + l15)*32 + quad*8];
            #pragma unroll
            for (int t = 0; t < 4; t++)
                bv[t] = *(const bf16x8*)&Vs[(t*16 + l15)*32 + quad*8];
            #pragma unroll
            for (int tm = 0; tm < 2; tm++)
                #pragma unroll
                for (int nd = 0; nd < 4; nd++)
                    oacc[tm][nd] = __builtin_amdgcn_mfma_f32_16x16x32_bf16(
                        ap[tm], bv[nd], oacc[tm][nd], 0, 0, 0);
        }
    }
    for (int tm = 0; tm < 2; tm++) for (int nd = 0; nd < 4; nd++)
        for (int r = 0; r < 4; r++) {
            int row = wv*32 + tm*16 + quad*4 + r;
            int grow = b*2048 + qt*128 + row;
            Obuf[(size_t)grow*1024 + h*64 + nd*16 + l15] = f2bf(oacc[tm][nd][r]);
        }
}

// ---------------------------------------------------------------------------
// 7) LayerNorm (fp32 in, fp32 out)
__global__ void k_ln(const float* G, const float* gamma, const float* beta,
                     float* out)
{
    int r = blockIdx.x, tid = threadIdx.x;
    float4 x = *(const float4*)&G[(size_t)r*1024 + tid*4];
    float s  = x.x + x.y + x.z + x.w;
    float sq = x.x*x.x + x.y*x.y + x.z*x.z + x.w*x.w;
    for (int d = 1; d < 64; d <<= 1) { s += __shfl_xor(s, d); sq += __shfl_xor(sq, d); }
    __shared__ float ssum[4], ssq[4];
    int wv = tid >> 6, lane = tid & 63;
    if (lane == 0) { ssum[wv] = s; ssq[wv] = sq; }
    __syncthreads();
    float ts = ssum[0] + ssum[1] + ssum[2] + ssum[3];
    float tq = ssq[0] + ssq[1] + ssq[2] + ssq[3];
    float mu  = ts * (1.0f/1024.0f);
    float var = tq * (1.0f/1024.0f) - mu*mu;
    float rs  = rsqrtf(var + 1e-6f);
    float4 o;
    int c = tid*4;
    o.x = (x.x - mu) * rs * gamma[c+0] + beta[c+0];
    o.y = (x.y - mu) * rs * gamma[c+1] + beta[c+1];
    o.z = (x.z - mu) * rs * gamma[c+2] + beta[c+2];
    o.w = (x.w - mu) * rs * gamma[c+3] + beta[c+3];
    *(float4*)&out[(size_t)r*1024 + c] = o;
}

// ---------------------------------------------------------------------------
extern "C" void kernel_launch(void* const* d_in, const int* in_sizes, int n_in,
                              void* d_out, int out_size, void* d_ws, size_t ws_size,
                              hipStream_t stream)
{
    const float* qkv   = (const float*)d_in[0];
    const int*   mask  = (const int*)d_in[1];
    const float* wq    = (const float*)d_in[2];
    const float* wk    = (const float*)d_in[3];
    const float* wvp   = (const float*)d_in[4];
    const float* wfc   = (const float*)d_in[5];
    const float* gamma = (const float*)d_in[6];
    const float* beta  = (const float*)d_in[7];

    unsigned short* R   = (unsigned short*)d_ws;
    float*          Wf  = (float*)d_ws;
    unsigned short* Vtb = R + U_VT;
    unsigned short* Ob  = R + U_QKV_HI;              // alias (dead after projections)
    float*          Gf  = Wf + F_G;                  // alias over lo+wq/wk copies
    unsigned long long* MB = (unsigned long long*)((char*)d_ws + B_MB);

    float* outp  = (float*)d_out;                    // [B,S,D] fp32
    float* attnp = outp + OUT0_ELEMS;                // [B,H,S,S] fp32

    k_split   <<<4096, 256, 0, stream>>>(qkv, R + U_QKV_HI, R + U_QKV_LO);
    k_wtrans  <<<dim3(16,16,4), 256, 0, stream>>>(wq, wk, wvp, wfc, R);
    k_maskpack<<<32768, 256, 0, stream>>>(mask, MB);
    k_gemm_qk <<<dim3(8,32,2), 256, 0, stream>>>(R, Wf);
    k_gemm_bf <<<dim3(8,32,1), 256, 0, stream>>>(R + U_QKV_HI, R + U_WV,
                                                 Vtb, nullptr, nullptr, 0);
    k_attn    <<<dim3(16,16,2), 256, 0, stream>>>(Wf + F_Q, Wf + F_K, Vtb, MB,
                                                  attnp, Ob);
    k_gemm_bf <<<dim3(8,32,1), 256, 0, stream>>>(Ob, R + U_WFC,
                                                 nullptr, Gf, qkv, 1);
    k_ln      <<<4096, 256, 0, stream>>>(Gf, gamma, beta, outp);
}

// Round 4
// 923.001 us; speedup vs baseline: 1.1632x; 1.1632x over previous
//
#include <hip/hip_runtime.h>
#include <stdint.h>

// All inputs/outputs FP32. bf16 MFMA with hi/lo split precision on the
// attn-critical path (qkv -> Q,K -> S). P written fp32 (exact-ish).
#define D_MODEL 1024
#define NHEAD   16
#define BATCH   2
#define SEQ     2048
#define MROWS   (BATCH*SEQ)                  // 4096
#define OUT0_ELEMS (MROWS*D_MODEL)           // 4194304
#define W_ELEMS    (D_MODEL*D_MODEL)

// workspace offsets (ushort element units). High-water ~64 MB.
#define U_QKVH 0            // qkv hi (4M)  -> later Ob (attn out, bf16)
#define U_QKVL 4194304      // qkv lo (4M)  -> later part of Gf
#define U_WQH  8388608      // wq hi (1M)   -> later Vt (4M spans 8M..12M)
#define U_WQL  9437184
#define U_WKH  10485760
#define U_WKL  11534336
#define U_WV   12582912     // wv bf16 (1M)
#define U_WFC  13631488     // wfc bf16 (1M)
#define U_QH   14680064     // Q hi bf16 [b,h,s,64] (4M)
#define U_QL   18874368
#define U_KH   23068672
#define U_KL   27262976
#define U_VT   8388608      // V^T bf16 [b,h,d,s] (4M) — overwrites wq/wk (dead)
#define U_MB   31457280     // mask bits (1 MB)
#define F_G    2097152      // float idx (byte 8388608): Gf fp32 over qkvl+Vt (dead)
#define PS_LD  80           // Ps row stride (bank-conflict-free for quad writes)

typedef __bf16  bf16x8 __attribute__((ext_vector_type(8)));
typedef float   f32x4  __attribute__((ext_vector_type(4)));

__device__ __forceinline__ float bf2f(unsigned short u) {
    union { unsigned int ui; float f; } v; v.ui = ((unsigned int)u) << 16; return v.f;
}
__device__ __forceinline__ unsigned short f2bf(float f) {
    union { float f; unsigned int u; } v; v.f = f;
    unsigned int u = v.u;
    return (unsigned short)((u + 0x7FFFu + ((u >> 16) & 1u)) >> 16);  // RNE
}
__device__ __forceinline__ void split2(float x, unsigned short& hi, unsigned short& lo) {
    hi = f2bf(x);
    lo = f2bf(x - bf2f(hi));
}
// async global->LDS, 16B per lane. LDS dest must be wave-uniform base + lane*16.
__device__ __forceinline__ void gld16(const void* g, void* l) {
    __builtin_amdgcn_global_load_lds(
        (const __attribute__((address_space(1))) unsigned int*)g,
        (__attribute__((address_space(3))) unsigned int*)l, 16, 0, 0);
}

// ---------------------------------------------------------------------------
// 1) qkv fp32 -> hi/lo bf16
__global__ void k_split(const float* in, unsigned short* hiA, unsigned short* loA)
{
    int i = (blockIdx.x * 256 + threadIdx.x) * 4;
    float4 x = *(const float4*)&in[i];
    ushort4 h, l;
    split2(x.x, h.x, l.x); split2(x.y, h.y, l.y);
    split2(x.z, h.z, l.z); split2(x.w, h.w, l.w);
    *(ushort4*)&hiA[i] = h;
    *(ushort4*)&loA[i] = l;
}

// ---------------------------------------------------------------------------
// 2) weights fp32 [k][n] -> transposed bf16 [n][k]; z<2 split hi/lo
__global__ void k_wtrans(const float* w0, const float* w1, const float* w2,
                         const float* w3, unsigned short* R)
{
    __shared__ __align__(16) float T[64][68];
    int z = blockIdx.z;
    const float* in = (z == 0) ? w0 : (z == 1) ? w1 : (z == 2) ? w2 : w3;
    const int hiOff[4] = {U_WQH, U_WKH, U_WV, U_WFC};
    const int loOff[2] = {U_WQL, U_WKL};
    unsigned short* outH = R + hiOff[z];
    unsigned short* outL = (z < 2) ? (R + loOff[z]) : nullptr;
    int bn = blockIdx.x, bk = blockIdx.y, tid = threadIdx.x;
    int r0 = tid >> 4, c = (tid & 15) * 4;
    for (int i = 0; i < 4; i++) {
        int r = r0 + i * 16;
        *(float4*)&T[r][c] = *(const float4*)&in[(bk*64 + r)*1024 + bn*64 + c];
    }
    __syncthreads();
    for (int i = 0; i < 4; i++) {
        int r = r0 + i * 16;
        ushort4 h, l;
        split2(T[c+0][r], h.x, l.x); split2(T[c+1][r], h.y, l.y);
        split2(T[c+2][r], h.z, l.z); split2(T[c+3][r], h.w, l.w);
        *(ushort4*)&outH[(bn*64 + r)*1024 + bk*64 + c] = h;
        if (z < 2) *(ushort4*)&outL[(bn*64 + r)*1024 + bk*64 + c] = l;
    }
}

// ---------------------------------------------------------------------------
// 3) Bit-pack mask (33.5 MB int32 -> 1 MB bits)
__global__ void k_maskpack(const int* mask, unsigned long long* mb)
{
    int w = blockIdx.x * 4 + (threadIdx.x >> 6);
    int lane = threadIdx.x & 63;
    int v = mask[(size_t)w * 64 + lane];
    unsigned long long bal = __ballot(v != 0);
    if (lane == 0) mb[w] = bal;
}

// ---------------------------------------------------------------------------
// 4) Split GEMM for Q (z=0, 1/8 folded) and K (z=1); writes hi/lo bf16 in
//    head-major [b,h,s,64] layout for contiguous k_attn staging.
__global__ __launch_bounds__(256)
void k_gemm_qk(const unsigned short* R, unsigned short* RW)
{
    __shared__ __align__(16) unsigned short Ah[8192], Al[8192];
    __shared__ __align__(16) unsigned short Bh[8192], Bl[8192];
    int tid = threadIdx.x, wv = tid >> 6, lane = tid & 63;
    int quad = lane >> 4, l15 = lane & 15;
    int m0 = blockIdx.y * 128, n0 = blockIdx.x * 128;
    int z = blockIdx.z;
    const unsigned short* Ahg = R + U_QKVH;
    const unsigned short* Alg = R + U_QKVL;
    const unsigned short* Bhg = R + (z == 0 ? U_WQH : U_WKH);
    const unsigned short* Blg = R + (z == 0 ? U_WQL : U_WKL);
    unsigned short* outH = RW + (z == 0 ? U_QH : U_KH);
    unsigned short* outL = RW + (z == 0 ? U_QL : U_KL);
    float scale = (z == 0) ? 0.125f : 1.0f;

    f32x4 zero4 = {0.f, 0.f, 0.f, 0.f};
    f32x4 acc[4][4];
    for (int a = 0; a < 4; a++) for (int b = 0; b < 4; b++) acc[a][b] = zero4;
    int wr = (wv >> 1) * 64, wc = (wv & 1) * 64;

    for (int k0 = 0; k0 < 1024; k0 += 64) {
        __syncthreads();
        for (int i = 0; i < 4; i++) {
            int e = (tid + 256*i) * 8, row = e >> 6, col = e & 63;
            gld16(&Ahg[(m0+row)*1024 + k0 + col], &Ah[e]);
            gld16(&Alg[(m0+row)*1024 + k0 + col], &Al[e]);
            gld16(&Bhg[(n0+row)*1024 + k0 + col], &Bh[e]);
            gld16(&Blg[(n0+row)*1024 + k0 + col], &Bl[e]);
        }
        __syncthreads();
        #pragma unroll
        for (int kc = 0; kc < 2; kc++) {
            bf16x8 ah[4], al[4], bh[4], bl[4];
            #pragma unroll
            for (int t = 0; t < 4; t++) {
                int ao = (wr + t*16 + l15)*64 + kc*32 + quad*8;
                int bo = (wc + t*16 + l15)*64 + kc*32 + quad*8;
                ah[t] = *(const bf16x8*)&Ah[ao];
                al[t] = *(const bf16x8*)&Al[ao];
                bh[t] = *(const bf16x8*)&Bh[bo];
                bl[t] = *(const bf16x8*)&Bl[bo];
            }
            #pragma unroll
            for (int tm = 0; tm < 4; tm++)
                #pragma unroll
                for (int tn = 0; tn < 4; tn++) {
                    acc[tm][tn] = __builtin_amdgcn_mfma_f32_16x16x32_bf16(ah[tm], bh[tn], acc[tm][tn], 0,0,0);
                    acc[tm][tn] = __builtin_amdgcn_mfma_f32_16x16x32_bf16(ah[tm], bl[tn], acc[tm][tn], 0,0,0);
                    acc[tm][tn] = __builtin_amdgcn_mfma_f32_16x16x32_bf16(al[tm], bh[tn], acc[tm][tn], 0,0,0);
                }
        }
    }
    for (int tm = 0; tm < 4; tm++) for (int tn = 0; tn < 4; tn++)
        for (int r = 0; r < 4; r++) {
            int row = m0 + wr + tm*16 + quad*4 + r;     // token
            int col = n0 + wc + tn*16 + l15;            // h*64+d
            int bb = row >> 11, s = row & 2047, hh = col >> 6, d = col & 63;
            size_t idx = ((size_t)(bb*16 + hh)*2048 + s)*64 + d;
            unsigned short hv, lv;
            split2(acc[tm][tn][r] * scale, hv, lv);
            outH[idx] = hv;
            outL[idx] = lv;
        }
}

// ---------------------------------------------------------------------------
// 5) Plain bf16 GEMM. mode 0: V-proj -> Vt [b,h,d,s]. mode 1: FC + residual -> Gf fp32
__global__ __launch_bounds__(256)
void k_gemm_bf(const unsigned short* A, const unsigned short* Bt,
               unsigned short* Vt, float* Gf, const float* resf, int mode)
{
    __shared__ __align__(16) unsigned short As[8192];
    __shared__ __align__(16) unsigned short Bs[8192];
    int tid = threadIdx.x, wv = tid >> 6, lane = tid & 63;
    int quad = lane >> 4, l15 = lane & 15;
    int m0 = blockIdx.y * 128, n0 = blockIdx.x * 128;
    f32x4 zero4 = {0.f, 0.f, 0.f, 0.f};
    f32x4 acc[4][4];
    for (int a = 0; a < 4; a++) for (int b = 0; b < 4; b++) acc[a][b] = zero4;
    int wr = (wv >> 1) * 64, wc = (wv & 1) * 64;

    for (int k0 = 0; k0 < 1024; k0 += 64) {
        __syncthreads();
        for (int i = 0; i < 4; i++) {
            int e = (tid + 256*i) * 8, row = e >> 6, col = e & 63;
            gld16(&A [(m0+row)*1024 + k0 + col], &As[e]);
            gld16(&Bt[(n0+row)*1024 + k0 + col], &Bs[e]);
        }
        __syncthreads();
        #pragma unroll
        for (int kc = 0; kc < 2; kc++) {
            bf16x8 af[4], bfr[4];
            #pragma unroll
            for (int t = 0; t < 4; t++) {
                af[t]  = *(const bf16x8*)&As[(wr + t*16 + l15)*64 + kc*32 + quad*8];
                bfr[t] = *(const bf16x8*)&Bs[(wc + t*16 + l15)*64 + kc*32 + quad*8];
            }
            #pragma unroll
            for (int tm = 0; tm < 4; tm++)
                #pragma unroll
                for (int tn = 0; tn < 4; tn++)
                    acc[tm][tn] = __builtin_amdgcn_mfma_f32_16x16x32_bf16(
                        af[tm], bfr[tn], acc[tm][tn], 0, 0, 0);
        }
    }
    for (int tm = 0; tm < 4; tm++) for (int tn = 0; tn < 4; tn++)
        for (int r = 0; r < 4; r++) {
            int row = m0 + wr + tm*16 + quad*4 + r;
            int col = n0 + wc + tn*16 + l15;
            float v = acc[tm][tn][r];
            if (mode == 1) {
                Gf[(size_t)row*1024 + col] = v + resf[(size_t)row*1024 + col];
            } else {
                int b = row >> 11, s = row & 2047, h = col >> 6, d = col & 63;
                Vt[(size_t)(((b*16 + h)*64 + d))*2048 + s] = f2bf(v);
            }
        }
}

// ---------------------------------------------------------------------------
// 6) Attention. Pre-split bf16 Q,K (head-major), K-tile 64, two-sweep no-max
//    softmax with recompute. P fp32 -> d_out; PV bf16 -> Ob.
__global__ __launch_bounds__(256)
void k_attn(const unsigned short* R, const unsigned long long* mb,
            float* Pout, unsigned short* Obuf)
{
    __shared__ __align__(16) unsigned short Qh[128*64], Ql[128*64];
    __shared__ __align__(16) unsigned short Kh[64*64],  Kl[64*64];
    __shared__ __align__(16) unsigned short Vs[64*64];
    __shared__ __align__(16) unsigned short Ps[128*PS_LD];
    int tid = threadIdx.x, wv = tid >> 6, lane = tid & 63;
    int quad = lane >> 4, l15 = lane & 15;
    int h = blockIdx.x, qt = blockIdx.y, b = blockIdx.z;
    int bh = b*16 + h;

    const unsigned short* Qhg = R + U_QH + ((size_t)bh*2048 + qt*128)*64;
    const unsigned short* Qlg = R + U_QL + ((size_t)bh*2048 + qt*128)*64;
    const unsigned short* Khg = R + U_KH + (size_t)bh*2048*64;
    const unsigned short* Klg = R + U_KL + (size_t)bh*2048*64;
    const unsigned short* Vtg = R + U_VT + (size_t)bh*64*2048;
    const unsigned long long* Mb = mb + (size_t)(b*2048 + qt*128)*32;
    float* Pg = Pout + ((size_t)bh*2048 + qt*128)*2048;

    for (int i = 0; i < 4; i++) {            // stage Q tile (fully linear)
        int e = (tid + 256*i)*8;
        gld16(&Qhg[e], &Qh[e]);
        gld16(&Qlg[e], &Ql[e]);
    }

    float lsum[8];
    for (int r = 0; r < 8; r++) lsum[r] = 0.f;
    f32x4 zero4 = {0.f, 0.f, 0.f, 0.f};

    // ---- sweep 1: denominators
    for (int kt = 0; kt < 32; kt++) {
        __syncthreads();
        for (int i = 0; i < 2; i++) {
            int e = (tid + 256*i)*8;
            gld16(&Khg[kt*4096 + e], &Kh[e]);
            gld16(&Klg[kt*4096 + e], &Kl[e]);
        }
        __syncthreads();
        f32x4 sacc[2][4];
        for (int a = 0; a < 2; a++) for (int c = 0; c < 4; c++) sacc[a][c] = zero4;
        #pragma unroll
        for (int kc = 0; kc < 2; kc++) {
            bf16x8 qh[2], ql[2], kh[4], kl[4];
            #pragma unroll
            for (int t = 0; t < 2; t++) {
                int qo = (wv*32 + t*16 + l15)*64 + kc*32 + quad*8;
                qh[t] = *(const bf16x8*)&Qh[qo]; ql[t] = *(const bf16x8*)&Ql[qo];
            }
            #pragma unroll
            for (int t = 0; t < 4; t++) {
                int ko = (t*16 + l15)*64 + kc*32 + quad*8;
                kh[t] = *(const bf16x8*)&Kh[ko]; kl[t] = *(const bf16x8*)&Kl[ko];
            }
            #pragma unroll
            for (int tm = 0; tm < 2; tm++)
                #pragma unroll
                for (int tn = 0; tn < 4; tn++) {
                    sacc[tm][tn] = __builtin_amdgcn_mfma_f32_16x16x32_bf16(qh[tm], kh[tn], sacc[tm][tn], 0,0,0);
                    sacc[tm][tn] = __builtin_amdgcn_mfma_f32_16x16x32_bf16(qh[tm], kl[tn], sacc[tm][tn], 0,0,0);
                    sacc[tm][tn] = __builtin_amdgcn_mfma_f32_16x16x32_bf16(ql[tm], kh[tn], sacc[tm][tn], 0,0,0);
                }
        }
        #pragma unroll
        for (int tm = 0; tm < 2; tm++)
            #pragma unroll
            for (int r = 0; r < 4; r++) {
                int row = wv*32 + tm*16 + quad*4 + r;
                unsigned long long w = Mb[row*32 + kt];
                float acc = 0.f;
                #pragma unroll
                for (int tn = 0; tn < 4; tn++)
                    if ((w >> (tn*16 + l15)) & 1ull) acc += __expf(sacc[tm][tn][r]);
                lsum[tm*4 + r] += acc;
            }
    }
    float invl[8];
    for (int r = 0; r < 8; r++) {
        float v = lsum[r];
        v += __shfl_xor(v, 1); v += __shfl_xor(v, 2);
        v += __shfl_xor(v, 4); v += __shfl_xor(v, 8);
        invl[r] = 1.0f / fmaxf(v, 1e-30f);
    }

    f32x4 oacc[2][4];
    for (int a = 0; a < 2; a++) for (int c = 0; c < 4; c++) oacc[a][c] = zero4;

    // ---- sweep 2: recompute S, write P, PV
    for (int kt = 0; kt < 32; kt++) {
        __syncthreads();
        for (int i = 0; i < 2; i++) {
            int e = (tid + 256*i)*8, d = e >> 6, s = e & 63;
            gld16(&Khg[kt*4096 + e], &Kh[e]);
            gld16(&Klg[kt*4096 + e], &Kl[e]);
            gld16(&Vtg[(size_t)d*2048 + kt*64 + s], &Vs[e]);
        }
        __syncthreads();
        f32x4 sacc[2][4];
        for (int a = 0; a < 2; a++) for (int c = 0; c < 4; c++) sacc[a][c] = zero4;
        #pragma unroll
        for (int kc = 0; kc < 2; kc++) {
            bf16x8 qh[2], ql[2], kh[4], kl[4];
            #pragma unroll
            for (int t = 0; t < 2; t++) {
                int qo = (wv*32 + t*16 + l15)*64 + kc*32 + quad*8;
                qh[t] = *(const bf16x8*)&Qh[qo]; ql[t] = *(const bf16x8*)&Ql[qo];
            }
            #pragma unroll
            for (int t = 0; t < 4; t++) {
                int ko = (t*16 + l15)*64 + kc*32 + quad*8;
                kh[t] = *(const bf16x8*)&Kh[ko]; kl[t] = *(const bf16x8*)&Kl[ko];
            }
            #pragma unroll
            for (int tm = 0; tm < 2; tm++)
                #pragma unroll
                for (int tn = 0; tn < 4; tn++) {
                    sacc[tm][tn] = __builtin_amdgcn_mfma_f32_16x16x32_bf16(qh[tm], kh[tn], sacc[tm][tn], 0,0,0);
                    sacc[tm][tn] = __builtin_amdgcn_mfma_f32_16x16x32_bf16(qh[tm], kl[tn], sacc[tm][tn], 0,0,0);
                    sacc[tm][tn] = __builtin_amdgcn_mfma_f32_16x16x32_bf16(ql[tm], kh[tn], sacc[tm][tn], 0,0,0);
                }
        }
        #pragma unroll
        for (int tm = 0; tm < 2; tm++)
            #pragma unroll
            for (int r = 0; r < 4; r++) {
                int row = wv*32 + tm*16 + quad*4 + r;
                unsigned long long w = Mb[row*32 + kt];
                float il = invl[tm*4 + r];
                #pragma unroll
                for (int tn = 0; tn < 4; tn++) {
                    float p = ((w >> (tn*16 + l15)) & 1ull)
                              ? __expf(sacc[tm][tn][r]) * il : 0.0f;
                    Ps[row*PS_LD + tn*16 + l15] = f2bf(p);
                    Pg[(size_t)row*2048 + kt*64 + tn*16 + l15] = p;
                }
            }
        // no barrier: each wave's Ps rows are written and read by itself
        #pragma unroll
        for (int kc = 0; kc < 2; kc++) {
            bf16x8 ap[2], bv[4];
            #pragma unroll
            for (int t = 0; t < 2; t++)
                ap[t] = *(const bf16x8*)&Ps[(wv*32 + t*16 + l15)*PS_LD + kc*32 + quad*8];
            #pragma unroll
            for (int t = 0; t < 4; t++)
                bv[t] = *(const bf16x8*)&Vs[(t*16 + l15)*64 + kc*32 + quad*8];
            #pragma unroll
            for (int tm = 0; tm < 2; tm++)
                #pragma unroll
                for (int nd = 0; nd < 4; nd++)
                    oacc[tm][nd] = __builtin_amdgcn_mfma_f32_16x16x32_bf16(
                        ap[tm], bv[nd], oacc[tm][nd], 0, 0, 0);
        }
    }
    for (int tm = 0; tm < 2; tm++) for (int nd = 0; nd < 4; nd++)
        for (int r = 0; r < 4; r++) {
            int row = wv*32 + tm*16 + quad*4 + r;
            int grow = b*2048 + qt*128 + row;
            Obuf[(size_t)grow*1024 + h*64 + nd*16 + l15] = f2bf(oacc[tm][nd][r]);
        }
}

// ---------------------------------------------------------------------------
// 7) LayerNorm fp32
__global__ void k_ln(const float* G, const float* gamma, const float* beta,
                     float* out)
{
    int r = blockIdx.x, tid = threadIdx.x;
    float4 x = *(const float4*)&G[(size_t)r*1024 + tid*4];
    float s  = x.x + x.y + x.z + x.w;
    float sq = x.x*x.x + x.y*x.y + x.z*x.z + x.w*x.w;
    for (int d = 1; d < 64; d <<= 1) { s += __shfl_xor(s, d); sq += __shfl_xor(sq, d); }
    __shared__ float ssum[4], ssq[4];
    int wv = tid >> 6, lane = tid & 63;
    if (lane == 0) { ssum[wv] = s; ssq[wv] = sq; }
    __syncthreads();
    float ts = ssum[0] + ssum[1] + ssum[2] + ssum[3];
    float tq = ssq[0] + ssq[1] + ssq[2] + ssq[3];
    float mu  = ts * (1.0f/1024.0f);
    float var = tq * (1.0f/1024.0f) - mu*mu;
    float rs  = rsqrtf(var + 1e-6f);
    float4 o;
    int c = tid*4;
    o.x = (x.x - mu) * rs * gamma[c+0] + beta[c+0];
    o.y = (x.y - mu) * rs * gamma[c+1] + beta[c+1];
    o.z = (x.z - mu) * rs * gamma[c+2] + beta[c+2];
    o.w = (x.w - mu) * rs * gamma[c+3] + beta[c+3];
    *(float4*)&out[(size_t)r*1024 + c] = o;
}

// ---------------------------------------------------------------------------
extern "C" void kernel_launch(void* const* d_in, const int* in_sizes, int n_in,
                              void* d_out, int out_size, void* d_ws, size_t ws_size,
                              hipStream_t stream)
{
    const float* qkv   = (const float*)d_in[0];
    const int*   mask  = (const int*)d_in[1];
    const float* wq    = (const float*)d_in[2];
    const float* wk    = (const float*)d_in[3];
    const float* wvp   = (const float*)d_in[4];
    const float* wfc   = (const float*)d_in[5];
    const float* gamma = (const float*)d_in[6];
    const float* beta  = (const float*)d_in[7];

    unsigned short* R   = (unsigned short*)d_ws;
    float*          Wf  = (float*)d_ws;
    unsigned short* Ob  = R + U_QKVH;                 // alias, dead after V-proj
    float*          Gf  = Wf + F_G;                   // alias over qkvl+Vt
    unsigned long long* MB = (unsigned long long*)(R + U_MB);

    float* outp  = (float*)d_out;                     // [B,S,D]
    float* attnp = outp + OUT0_ELEMS;                 // [B,H,S,S]

    k_split   <<<4096, 256, 0, stream>>>(qkv, R + U_QKVH, R + U_QKVL);
    k_wtrans  <<<dim3(16,16,4), 256, 0, stream>>>(wq, wk, wvp, wfc, R);
    k_maskpack<<<32768, 256, 0, stream>>>(mask, MB);
    k_gemm_qk <<<dim3(8,32,2), 256, 0, stream>>>(R, R);
    k_gemm_bf <<<dim3(8,32,1), 256, 0, stream>>>(R + U_QKVH, R + U_WV,
                                                 R + U_VT, nullptr, nullptr, 0);
    k_attn    <<<dim3(16,16,2), 256, 0, stream>>>(R, MB, attnp, Ob);
    k_gemm_bf <<<dim3(8,32,1), 256, 0, stream>>>(Ob, R + U_WFC,
                                                 nullptr, Gf, qkv, 1);
    k_ln      <<<4096, 256, 0, stream>>>(Gf, gamma, beta, outp);
}